// Round 1
// baseline (155.438 us; speedup 1.0000x reference)
//
#include <hip/hip_runtime.h>
#include <math.h>

// EdgeDetailAggregateLoss fused kernel for MI355X.
// B=32, H=W=512. targets: NHWC C=2 f32; network_output: NHWC C=1 f32.
// Output: scalar focal-loss sum.

#define B_ 32
#define H_ 512
#define W_ 512

constexpr int TY = 64;     // output tile rows per block
constexpr int TX = 64;     // output tile cols per block
constexpr int RR = 71;     // staged halo region: [y0-4, y0+66]
constexpr int SSTR = 73;   // LDS row stride (73 mod 32 = 9 -> conflict-light)

__global__ void zero_acc(double* acc) { acc[0] = 0.0; }

__global__ void finalize(const double* __restrict__ acc, float* __restrict__ out) {
    out[0] = (float)acc[0];
}

__global__ __launch_bounds__(256) void edge_focal_kernel(
    const float* __restrict__ net,   // [B,H,W,1]
    const float* __restrict__ tgt,   // [B,H,W,2]
    double* __restrict__ acc)
{
    __shared__ float sT[RR * SSTR];   // t0+t1 halo tile
    __shared__ float sB2[34 * 36];    // clipped stride-2 conv grid (<=33x33)
    __shared__ float sB4[18 * 20];    // clipped stride-4 conv grid (<=17x17)
    __shared__ float sRed[4];

    const int tid = threadIdx.x;
    const int x0 = blockIdx.x * TX;
    const int y0 = blockIdx.y * TY;
    const int b  = blockIdx.z;

    // ---- Phase 1: stage s = t0 + t1 over [y0-4, y0+66] x [x0-4, x0+66], zero-padded
    const float* tb = tgt + (size_t)b * (H_ * W_ * 2);
    for (int idx = tid; idx < RR * RR; idx += 256) {
        int r = idx / RR;
        int c = idx - r * RR;
        int gy = y0 - 4 + r;
        int gx = x0 - 4 + c;
        float v = 0.f;
        if ((unsigned)gy < (unsigned)H_ && (unsigned)gx < (unsigned)W_) {
            const float2 t2 = *reinterpret_cast<const float2*>(tb + ((size_t)gy * W_ + gx) * 2);
            v = t2.x + t2.y;
        }
        sT[r * SSTR + c] = v;
    }
    __syncthreads();

    // align-corners interp scales, f64 divide then f32 cast (matches reference)
    const float s2 = (float)(255.0 / 511.0);
    const float s4 = (float)(127.0 / 511.0);

    // ---- Phase 2: stride-2 conv grid (SAME pad: lo=0, hi=1 -> window rows 2r..2r+2)
    const int r2lo = (int)((float)y0 * s2);
    const int c2lo = (int)((float)x0 * s2);
    const int r2hi = min((int)((float)(y0 + TY - 1) * s2) + 1, 255);
    const int c2hi = min((int)((float)(x0 + TX - 1) * s2) + 1, 255);
    const int n2r = r2hi - r2lo + 1, n2c = c2hi - c2lo + 1;

    for (int idx = tid; idx < n2r * n2c; idx += 256) {
        int rr = idx / n2c, cc = idx - rr * n2c;
        int ly = 2 * (r2lo + rr) - (y0 - 4);
        int lx = 2 * (c2lo + cc) - (x0 - 4);
        const float* q0 = &sT[ly * SSTR + lx];
        const float* q1 = q0 + SSTR;
        const float* q2 = q1 + SSTR;
        float s9 = q0[0] + q0[1] + q0[2] + q1[0] + q1[1] + q1[2] + q2[0] + q2[1] + q2[2];
        float cv = 9.f * q1[1] - s9;          // 8*center - neighbors
        sB2[rr * 36 + cc] = fminf(fmaxf(cv, 0.f), 1.f);
    }

    // ---- Phase 3: stride-4 conv grid (no pad -> window rows 4r..4r+2)
    const int r4lo = (int)((float)y0 * s4);
    const int c4lo = (int)((float)x0 * s4);
    const int r4hi = min((int)((float)(y0 + TY - 1) * s4) + 1, 127);
    const int c4hi = min((int)((float)(x0 + TX - 1) * s4) + 1, 127);
    const int n4r = r4hi - r4lo + 1, n4c = c4hi - c4lo + 1;

    for (int idx = tid; idx < n4r * n4c; idx += 256) {
        int rr = idx / n4c, cc = idx - rr * n4c;
        int ly = 4 * (r4lo + rr) - (y0 - 4);
        int lx = 4 * (c4lo + cc) - (x0 - 4);
        const float* q0 = &sT[ly * SSTR + lx];
        const float* q1 = q0 + SSTR;
        const float* q2 = q1 + SSTR;
        float s9 = q0[0] + q0[1] + q0[2] + q1[0] + q1[1] + q1[2] + q2[0] + q2[1] + q2[2];
        float cv = 9.f * q1[1] - s9;
        sB4[rr * 20 + cc] = fminf(fmaxf(cv, 0.f), 1.f);
    }
    __syncthreads();

    // ---- Phase 4: per-pixel fuse + focal loss
    const float* nb = net + (size_t)b * (H_ * W_);
    float facc = 0.f;

    for (int it = 0; it < 16; ++it) {
        int py = it * 4 + (tid >> 6);   // 0..63
        int px = tid & 63;              // 0..63
        int gy = y0 + py;
        int gx = x0 + px;
        int ly = py + 4;
        int lx = px + 4;

        // e1: stride-1 conv (pad 1,1), clip>0.1 == conv>0.1
        const float* rm = &sT[(ly - 1) * SSTR + (lx - 1)];
        const float* r0 = rm + SSTR;
        const float* rp = r0 + SSTR;
        float s9 = rm[0] + rm[1] + rm[2] + r0[0] + r0[1] + r0[2] + rp[0] + rp[1] + rp[2];
        float cv1 = 9.f * r0[1] - s9;
        float e1 = (cv1 > 0.1f) ? 1.f : 0.f;

        // e2: bilinear (align-corners) of clipped stride-2 grid, rows then cols
        float posy = (float)gy * s2; int i0 = (int)posy; float wy = posy - (float)i0;
        int i1 = min(i0 + 1, 255);
        float posx = (float)gx * s2; int j0 = (int)posx; float wx = posx - (float)j0;
        int j1 = min(j0 + 1, 255);
        {
            int a0 = i0 - r2lo, a1 = i1 - r2lo, b0 = j0 - c2lo, b1 = j1 - c2lo;
            float v00 = sB2[a0 * 36 + b0], v01 = sB2[a0 * 36 + b1];
            float v10 = sB2[a1 * 36 + b0], v11 = sB2[a1 * 36 + b1];
            float ta = v00 * (1.f - wy) + v10 * wy;
            float tb2 = v01 * (1.f - wy) + v11 * wy;
            float v2 = ta * (1.f - wx) + tb2 * wx;
            e1 = e1; // keep
            float e2 = (v2 > 0.1f) ? 1.f : 0.f;

            // e4
            float posy4 = (float)gy * s4; int k0 = (int)posy4; float wy4 = posy4 - (float)k0;
            int k1 = min(k0 + 1, 127);
            float posx4 = (float)gx * s4; int l0 = (int)posx4; float wx4 = posx4 - (float)l0;
            int l1 = min(l0 + 1, 127);
            int u0 = k0 - r4lo, u1 = k1 - r4lo, w0 = l0 - c4lo, w1 = l1 - c4lo;
            float z00 = sB4[u0 * 20 + w0], z01 = sB4[u0 * 20 + w1];
            float z10 = sB4[u1 * 20 + w0], z11 = sB4[u1 * 20 + w1];
            float za = z00 * (1.f - wy4) + z10 * wy4;
            float zb = z01 * (1.f - wy4) + z11 * wy4;
            float v4 = za * (1.f - wx4) + zb * wx4;
            float e4 = (v4 > 0.1f) ? 1.f : 0.f;

            // fuse conv (1x1, weights .6/.3/.1) + threshold
            float fv = 0.6f * e1 + 0.3f * e2 + 0.1f * e4;
            bool pos = fv > 0.1f;

            // focal loss term
            float p = nb[(size_t)gy * W_ + gx];
            float q  = pos ? p : (1.f - p);
            float al = pos ? 0.25f : 0.75f;
            float lg = fmaxf(logf(q), -100.f);
            float om = 1.f - q;
            facc += al * (-lg) * (om * om);
        }
    }

    // ---- Reduce: wave64 shuffle -> cross-wave LDS -> one double atomic per block
    for (int off = 32; off > 0; off >>= 1)
        facc += __shfl_down(facc, off);
    int wid = tid >> 6;
    if ((tid & 63) == 0) sRed[wid] = facc;
    __syncthreads();
    if (tid == 0) {
        float s = sRed[0] + sRed[1] + sRed[2] + sRed[3];
        atomicAdd(acc, (double)s);
    }
}

extern "C" void kernel_launch(void* const* d_in, const int* in_sizes, int n_in,
                              void* d_out, int out_size, void* d_ws, size_t ws_size,
                              hipStream_t stream) {
    const float* net = (const float*)d_in[0];   // network_output
    const float* tgt = (const float*)d_in[1];   // targets
    // d_in[2] = laplacian, d_in[3] = fuse_kernel: fixed constants, baked into the kernel.
    double* acc = (double*)d_ws;
    float* out = (float*)d_out;

    hipLaunchKernelGGL(zero_acc, dim3(1), dim3(1), 0, stream, acc);
    hipLaunchKernelGGL(edge_focal_kernel, dim3(W_ / TX, H_ / TY, B_), dim3(256), 0, stream,
                       net, tgt, acc);
    hipLaunchKernelGGL(finalize, dim3(1), dim3(1), 0, stream, acc, out);
}

// Round 3
// 129.839 us; speedup vs baseline: 1.1972x; 1.1972x over previous
//
#include <hip/hip_runtime.h>
#include <math.h>

// EdgeDetailAggregateLoss fused kernel for MI355X (gfx950).
// B=32, H=W=512. targets: NHWC C=2 f32; network_output: NHWC C=1 f32.
// Output: scalar focal-loss sum.
//
// Key simplification (bit-exact): fused mask = (0.6*e1 + 0.3*e2 + 0.1*e4 > 0.1f)
// with e* in {0,1}. 0.1f*1 == 0.1f is NOT > 0.1f, and any passing combo already
// has e1 or e2 set  =>  pos == e1 || e2. The whole stride-4 branch is dead.

#define B_ 32
#define H_ 512
#define W_ 512

constexpr int TY = 32;     // output tile rows per block
constexpr int TX = 64;     // output tile cols per block
constexpr int RRY = 37;    // staged rows [y0-2, y0+34]
constexpr int RRX = 69;    // staged cols [x0-2, x0+66]
constexpr int SSTR = 70;   // even stride -> aligned float2 LDS writes; 70%32=6

__global__ __launch_bounds__(256, 8) void edge_focal_kernel(
    const float* __restrict__ net,   // [B,H,W,1]
    const float* __restrict__ tgt,   // [B,H,W,2]
    double* __restrict__ partial)    // [gridDim.z*gridDim.y*gridDim.x]
{
    __shared__ float sT[RRY * SSTR];   // t0+t1 halo tile (laplacian is same for both ch)
    __shared__ float sB2[18 * 36];     // clipped stride-2 conv grid (<=17x33)
    __shared__ double sRed[4];

    const int tid = threadIdx.x;
    const int x0 = blockIdx.x * TX;
    const int y0 = blockIdx.y * TY;
    const int b  = blockIdx.z;

    // ---- Phase 1: stage s = t0+t1 over [y0-2,y0+34] x [x0-2,x0+66], zero-padded.
    // Column pairs c2=0..34 cover local cols 0..69 (col 69 is scratch).
    const float* tb = tgt + (size_t)b * (H_ * W_ * 2);
    for (int idx = tid; idx < RRY * 35; idx += 256) {
        int r  = idx / 35;
        int c2 = idx - r * 35;
        int gy = y0 - 2 + r;
        int gx = x0 - 2 + 2 * c2;
        float v0 = 0.f, v1 = 0.f;
        if ((unsigned)gy < (unsigned)H_) {
            if (gx >= 0 && gx + 1 < W_) {   // interior: one float4 = 2 pixels
                const float4 q = *reinterpret_cast<const float4*>(tb + ((size_t)gy * W_ + gx) * 2);
                v0 = q.x + q.y; v1 = q.z + q.w;
            } else {
                if ((unsigned)gx < (unsigned)W_) {
                    const float2 t2 = *reinterpret_cast<const float2*>(tb + ((size_t)gy * W_ + gx) * 2);
                    v0 = t2.x + t2.y;
                }
                if ((unsigned)(gx + 1) < (unsigned)W_) {
                    const float2 t2 = *reinterpret_cast<const float2*>(tb + ((size_t)gy * W_ + gx + 1) * 2);
                    v1 = t2.x + t2.y;
                }
            }
        }
        sT[r * SSTR + 2 * c2]     = v0;
        sT[r * SSTR + 2 * c2 + 1] = v1;
    }
    __syncthreads();

    // align-corners interp scale, f64 divide then f32 cast (matches reference exactly)
    const float s2 = (float)(255.0 / 511.0);

    // ---- Phase 2: stride-2 conv grid (SAME pad lo=0,hi=1 -> window rows 2r..2r+2)
    const int r2lo = (int)((float)y0 * s2);
    const int c2lo = (int)((float)x0 * s2);
    const int r2hi = min((int)((float)(y0 + TY - 1) * s2) + 1, 255);
    const int c2hi = min((int)((float)(x0 + TX - 1) * s2) + 1, 255);
    const int n2r = r2hi - r2lo + 1, n2c = c2hi - c2lo + 1;

    for (int idx = tid; idx < 18 * 36; idx += 256) {
        int rr = idx / 36, cc = idx - rr * 36;
        if (rr < n2r && cc < n2c) {
            int ly = 2 * (r2lo + rr) - (y0 - 2);
            int lx = 2 * (c2lo + cc) - (x0 - 2);
            const float* q0 = &sT[ly * SSTR + lx];
            const float* q1 = q0 + SSTR;
            const float* q2 = q1 + SSTR;
            float s9 = q0[0] + q0[1] + q0[2] + q1[0] + q1[1] + q1[2] + q2[0] + q2[1] + q2[2];
            float cv = 9.f * q1[1] - s9;   // 8*center - neighbors
            sB2[idx] = fminf(fmaxf(cv, 0.f), 1.f);
        }
    }
    __syncthreads();

    // ---- Phase 4: per-pixel fuse + focal. Wave w owns rows [w*8, w*8+8): rolling conv rows.
    const float* nb = net + (size_t)b * (H_ * W_);
    const int lane = tid & 63;
    const int wv   = tid >> 6;
    const int py0  = wv * 8;
    const int gx   = x0 + lane;
    const int lx   = lane + 2;

    // per-lane x-interp constants (hoisted out of the row loop)
    const float posx = (float)gx * s2;
    const int   j0   = (int)posx;
    const int   j1   = min(j0 + 1, 255);
    const float wx   = posx - (float)j0;
    const int   bc0  = j0 - c2lo, bc1 = j1 - c2lo;

    // prefetch the 8 network_output values (coalesced; hides HBM latency under compute)
    float p[8];
    #pragma unroll
    for (int i = 0; i < 8; ++i)
        p[i] = nb[(size_t)(y0 + py0 + i) * W_ + gx];

    // rolling 3-wide row sums for the stride-1 conv
    const float* row = &sT[(py0 + 1) * SSTR + lx - 1];   // row ly-1 of first pixel
    float rs_m = row[0] + row[1] + row[2];
    row += SSTR;                                          // row ly
    float c_c = row[1];
    float rs_c = row[0] + c_c + row[2];

    float facc = 0.f;
    #pragma unroll
    for (int i = 0; i < 8; ++i) {
        const int py = py0 + i;
        const int gy = y0 + py;
        row = &sT[(py + 3) * SSTR + lx - 1];              // row ly+1
        const float n0 = row[0], n1 = row[1], n2 = row[2];
        const float rs_p = n0 + n1 + n2;

        const float cv1 = 9.f * c_c - (rs_m + rs_c + rs_p);
        const bool e1 = cv1 > 0.1f;

        // bilinear (align-corners) of clipped stride-2 grid: rows first, then cols
        const float posy = (float)gy * s2;
        const int   i0   = (int)posy;
        const int   i1   = min(i0 + 1, 255);
        const float wy   = posy - (float)i0;
        const int   a0   = i0 - r2lo, a1 = i1 - r2lo;
        const float v00 = sB2[a0 * 36 + bc0], v01 = sB2[a0 * 36 + bc1];
        const float v10 = sB2[a1 * 36 + bc0], v11 = sB2[a1 * 36 + bc1];
        const float ta  = v00 * (1.f - wy) + v10 * wy;
        const float tb2 = v01 * (1.f - wy) + v11 * wy;
        const float v2  = ta * (1.f - wx) + tb2 * wx;
        const bool e2 = v2 > 0.1f;

        const bool pos = e1 || e2;      // exact: 0.1*e4 alone can never exceed 0.1f
        const float pv = p[i];
        const float q  = pos ? pv : 1.f - pv;
        const float al = pos ? 0.25f : 0.75f;
        const float lg = fmaxf(logf(q), -100.f);
        const float om = 1.f - q;
        facc += al * (-lg) * (om * om);

        rs_m = rs_c; rs_c = rs_p; c_c = n1;
    }

    // ---- Reduce: wave shuffle -> cross-wave LDS -> one partial per block (no atomics)
    #pragma unroll
    for (int off = 32; off > 0; off >>= 1)
        facc += __shfl_down(facc, off);
    if (lane == 0) sRed[wv] = (double)facc;
    __syncthreads();
    if (tid == 0) {
        partial[((size_t)blockIdx.z * gridDim.y + blockIdx.y) * gridDim.x + blockIdx.x] =
            sRed[0] + sRed[1] + sRed[2] + sRed[3];
    }
}

__global__ __launch_bounds__(256) void reduce_partials(
    const double* __restrict__ partial, float* __restrict__ out, int n)
{
    __shared__ double sRed[4];
    double s = 0.0;
    for (int i = threadIdx.x; i < n; i += 256) s += partial[i];
    #pragma unroll
    for (int off = 32; off > 0; off >>= 1)
        s += __shfl_down(s, off);
    if ((threadIdx.x & 63) == 0) sRed[threadIdx.x >> 6] = s;
    __syncthreads();
    if (threadIdx.x == 0) out[0] = (float)(sRed[0] + sRed[1] + sRed[2] + sRed[3]);
}

extern "C" void kernel_launch(void* const* d_in, const int* in_sizes, int n_in,
                              void* d_out, int out_size, void* d_ws, size_t ws_size,
                              hipStream_t stream) {
    const float* net = (const float*)d_in[0];   // network_output
    const float* tgt = (const float*)d_in[1];   // targets
    // d_in[2] = laplacian, d_in[3] = fuse_kernel: fixed constants baked in.
    double* partial = (double*)d_ws;            // 4096 doubles = 32 KB scratch
    float* out = (float*)d_out;

    const dim3 grid(W_ / TX, H_ / TY, B_);      // 8 x 16 x 32 = 4096 blocks
    hipLaunchKernelGGL(edge_focal_kernel, grid, dim3(256), 0, stream, net, tgt, partial);
    hipLaunchKernelGGL(reduce_partials, dim3(1), dim3(256), 0, stream,
                       partial, out, (int)(grid.x * grid.y * grid.z));
}